// Round 3
// baseline (421.650 us; speedup 1.0000x reference)
//
#include <hip/hip_runtime.h>
#include <math.h>

// SparseExpertCountingNetwork: N=131072 rows, H=2048, E=4 experts.
// out[n] = sum_e softmax(hist[n]@W.T + b + gumbel(u[n]))_e * expert_e(hist[n])
// experts = [sum, max/(sum+1e-6), count(!=0), count(adjacent !=)]
//
// HBM-bound (1.074 GB hist stream). R3 design:
//  - one wave per row; rows processed in PAIRS sharing W-fragment reads
//  - W staged in LDS (32 KB/block) instead of 128 VGPRs -> launch_bounds(256,4)
//    doubles occupancy to 16 waves/CU (TLP covers HBM latency; no ping-pong)
//  - volatile LDS reads so loop-invariant W loads are NOT hoisted into regs
//  - wave reductions via DPP (row_shr + row_bcast, VALU-only, lane 63 result)
//    -> near-zero DS-pipe traffic (no ds_swizzle butterfly, no shfl carry)
//  - pattern-count boundary element re-loaded from cache (hr[c-1]) instead of
//    cross-lane shuffles

#define HDIM 2048
#define NITER 8  // HDIM / (64 lanes * 4 floats)

typedef float f32x4 __attribute__((ext_vector_type(4)));

// DPP full-wave reductions (VALU-only). After row_shr:1/2/4/8 + row_bcast:15
// + row_bcast:31, lane 63 holds the 64-lane result.
#define DPP_ADD(x, ctrl)                                                     \
  (x) += __int_as_float(__builtin_amdgcn_update_dpp(                         \
      0, __float_as_int(x), (ctrl), 0xF, 0xF, false))
#define DPP_MAX(x, ctrl)                                                     \
  do {                                                                       \
    float _t = __int_as_float(__builtin_amdgcn_update_dpp(                   \
        __float_as_int(x), __float_as_int(x), (ctrl), 0xF, 0xF, false));     \
    (x) = fmaxf((x), _t);                                                    \
  } while (0)

__device__ __forceinline__ float wave_sum63(float x) {
  DPP_ADD(x, 0x111); DPP_ADD(x, 0x112); DPP_ADD(x, 0x114); DPP_ADD(x, 0x118);
  DPP_ADD(x, 0x142); DPP_ADD(x, 0x143);
  return x;  // valid in lane 63
}
__device__ __forceinline__ float wave_max63(float x) {
  DPP_MAX(x, 0x111); DPP_MAX(x, 0x112); DPP_MAX(x, 0x114); DPP_MAX(x, 0x118);
  DPP_MAX(x, 0x142); DPP_MAX(x, 0x143);
  return x;  // valid in lane 63
}

__global__ __launch_bounds__(256, 4) void moe_fused_kernel(
    const float* __restrict__ hist, const float* __restrict__ W,
    const float* __restrict__ bias, const float* __restrict__ gu,
    float* __restrict__ out, int N)
{
  __shared__ float Wl[4 * HDIM];  // 32 KB router weights, block-shared
  {
    f32x4* dst = (f32x4*)Wl;
    const f32x4* src = (const f32x4*)W;
    for (int i = threadIdx.x; i < (4 * HDIM) / 4; i += 256) dst[i] = src[i];
  }
  __syncthreads();  // only barrier in the kernel

  const int lane  = threadIdx.x & 63;
  const int wid   = threadIdx.x >> 6;
  const int gw    = blockIdx.x * 4 + wid;  // global wave id
  const int GW    = gridDim.x * 4;         // total waves
  const int cbase = 4 * lane;
  const float b0 = bias[0], b1 = bias[1], b2 = bias[2], b3 = bias[3];

  for (int rA = gw; rA < N; rA += 2 * GW) {
    const int  rBn  = rA + GW;
    const bool hasB = rBn < N;
    const int  rB   = hasB ? rBn : rA;  // degenerate pair on odd tail

    const float* hrA = hist + (size_t)rA * HDIM;
    const float* hrB = hist + (size_t)rB * HDIM;

    // Issue all streaming loads up front (nontemporal: one-pass 1 GB stream)
    f32x4 hA[NITER], hB[NITER];
#pragma unroll
    for (int j = 0; j < NITER; ++j)
      hA[j] = __builtin_nontemporal_load((const f32x4*)(hrA + 256 * j + cbase));
#pragma unroll
    for (int j = 0; j < NITER; ++j)
      hB[j] = __builtin_nontemporal_load((const f32x4*)(hrB + 256 * j + cbase));
    const f32x4 uA = *(const f32x4*)(gu + (size_t)rA * 4);
    const f32x4 uB = *(const f32x4*)(gu + (size_t)rB * 4);

    float dA0=0.f,dA1=0.f,dA2=0.f,dA3=0.f, totA=0.f, cntA=0.f, mxA=-3.4e38f;
    float dB0=0.f,dB1=0.f,dB2=0.f,dB3=0.f, totB=0.f, cntB=0.f, mxB=-3.4e38f;

#pragma unroll
    for (int j = 0; j < NITER; ++j) {
      const int c  = 256 * j + cbase;
      const int ci = c ? c - 1 : 0;  // clamp: at c==0 compares v.x!=v.x -> 0
      // W fragments from LDS, shared across both rows of the pair.
      // volatile keeps these reads in-loop (prevents LICM re-hoist to VGPRs).
      f32x4 w0 = *(const volatile f32x4*)(Wl + 0 * HDIM + c);
      f32x4 w1 = *(const volatile f32x4*)(Wl + 1 * HDIM + c);
      f32x4 w2 = *(const volatile f32x4*)(Wl + 2 * HDIM + c);
      f32x4 w3 = *(const volatile f32x4*)(Wl + 3 * HDIM + c);
      const float pvA = hrA[ci];  // boundary elem: cache hit (line just fetched)
      const float pvB = hrB[ci];
      {
        f32x4 v = hA[j];
        dA0 += v.x*w0.x + v.y*w0.y + v.z*w0.z + v.w*w0.w;
        dA1 += v.x*w1.x + v.y*w1.y + v.z*w1.z + v.w*w1.w;
        dA2 += v.x*w2.x + v.y*w2.y + v.z*w2.z + v.w*w2.w;
        dA3 += v.x*w3.x + v.y*w3.y + v.z*w3.z + v.w*w3.w;
        totA += (v.x + v.y) + (v.z + v.w);
        mxA = fmaxf(mxA, fmaxf(fmaxf(v.x, v.y), fmaxf(v.z, v.w)));
        cntA += 4096.f * ((v.x != 0.f ? 1.f : 0.f) + (v.y != 0.f ? 1.f : 0.f)
                        + (v.z != 0.f ? 1.f : 0.f) + (v.w != 0.f ? 1.f : 0.f));
        cntA += (v.x != pvA ? 1.f : 0.f) + (v.y != v.x ? 1.f : 0.f)
              + (v.z != v.y ? 1.f : 0.f) + (v.w != v.z ? 1.f : 0.f);
      }
      {
        f32x4 v = hB[j];
        dB0 += v.x*w0.x + v.y*w0.y + v.z*w0.z + v.w*w0.w;
        dB1 += v.x*w1.x + v.y*w1.y + v.z*w1.z + v.w*w1.w;
        dB2 += v.x*w2.x + v.y*w2.y + v.z*w2.z + v.w*w2.w;
        dB3 += v.x*w3.x + v.y*w3.y + v.z*w3.z + v.w*w3.w;
        totB += (v.x + v.y) + (v.z + v.w);
        mxB = fmaxf(mxB, fmaxf(fmaxf(v.x, v.y), fmaxf(v.z, v.w)));
        cntB += 4096.f * ((v.x != 0.f ? 1.f : 0.f) + (v.y != 0.f ? 1.f : 0.f)
                        + (v.z != 0.f ? 1.f : 0.f) + (v.w != 0.f ? 1.f : 0.f));
        cntB += (v.x != pvB ? 1.f : 0.f) + (v.y != v.x ? 1.f : 0.f)
              + (v.z != v.y ? 1.f : 0.f) + (v.w != v.z ? 1.f : 0.f);
      }
    }

    // VALU-only wave reductions; results valid in lane 63
    dA0 = wave_sum63(dA0); dA1 = wave_sum63(dA1);
    dA2 = wave_sum63(dA2); dA3 = wave_sum63(dA3);
    totA = wave_sum63(totA); cntA = wave_sum63(cntA); mxA = wave_max63(mxA);
    dB0 = wave_sum63(dB0); dB1 = wave_sum63(dB1);
    dB2 = wave_sum63(dB2); dB3 = wave_sum63(dB3);
    totB = wave_sum63(totB); cntB = wave_sum63(cntB); mxB = wave_max63(mxB);

    // Epilogue (computed on all lanes, only lane 63's values are valid)
    auto finish = [&](float d0, float d1, float d2, float d3, float tot,
                      float cnt, float mx, f32x4 u4) -> float {
      float uq = floorf(cnt * (1.f / 4096.f));
      float pc = cnt - 4096.f * uq;
      float z0 = d0 + b0, z1 = d1 + b1, z2 = d2 + b2, z3 = d3 + b3;
      float ux = fminf(fmaxf(u4.x, 1e-6f), 1.f - 1e-6f);
      float uy = fminf(fmaxf(u4.y, 1e-6f), 1.f - 1e-6f);
      float uz = fminf(fmaxf(u4.z, 1e-6f), 1.f - 1e-6f);
      float uw = fminf(fmaxf(u4.w, 1e-6f), 1.f - 1e-6f);
      z0 += -logf(-logf(ux));
      z1 += -logf(-logf(uy));
      z2 += -logf(-logf(uz));
      z3 += -logf(-logf(uw));
      float m  = fmaxf(fmaxf(z0, z1), fmaxf(z2, z3));
      float p0 = expf(z0 - m), p1 = expf(z1 - m);
      float p2 = expf(z2 - m), p3 = expf(z3 - m);
      float inv = 1.f / (p0 + p1 + p2 + p3);
      float freq = mx / (tot + 1e-6f);
      return (p0 * tot + p1 * freq + p2 * uq + p3 * pc) * inv;
    };

    float resA = finish(dA0, dA1, dA2, dA3, totA, cntA, mxA, uA);
    float resB = finish(dB0, dB1, dB2, dB3, totB, cntB, mxB, uB);
    if (lane == 63) {
      out[rA] = resA;
      if (hasB) out[rB] = resB;
    }
  }
}

extern "C" void kernel_launch(void* const* d_in, const int* in_sizes, int n_in,
                              void* d_out, int out_size, void* d_ws, size_t ws_size,
                              hipStream_t stream) {
    const float* hist = (const float*)d_in[0];  // [N, 2048]
    const float* W    = (const float*)d_in[1];  // [4, 2048]
    const float* b    = (const float*)d_in[2];  // [4]
    const float* gu   = (const float*)d_in[3];  // [N, 4]
    float* out = (float*)d_out;                 // [N]
    const int N = out_size;

    // 1024 blocks * 4 waves = 4096 waves = exactly one full-residency batch
    // at 4 blocks/CU * 256 CUs; 32 rows (16 pairs) per wave.
    dim3 grid(1024), block(256);
    moe_fused_kernel<<<grid, block, 0, stream>>>(hist, W, b, gu, out, N);
}

// Round 4
// 181.144 us; speedup vs baseline: 2.3277x; 2.3277x over previous
//
#include <hip/hip_runtime.h>
#include <math.h>

// SparseExpertCountingNetwork: N=131072 rows, H=2048, E=4 experts.
// out[n] = sum_e softmax(hist[n]@W.T + b + gumbel(u[n]))_e * expert_e(hist[n])
// experts = [sum, max/(sum+1e-6), count(!=0), count(adjacent !=)]
//
// HBM-bound (1.074 GB hist stream). R4 = R2 (proven 190.9 us) with the DS
// pipe removed entirely:
//  - one wave per row, W register-resident (128 VGPRs), 2-row ping-pong
//  - wave reductions via DPP row_shr/row_bcast (VALU-only, result in lane 63)
//  - pattern-count boundary via DPP wave_shr:1 + v_readlane carry (VALU-only)
//  - kernel has ZERO LDS/DS instructions: pure VMEM + VALU

#define HDIM 2048
#define NITER 8  // HDIM / (64 lanes * 4 floats)

typedef float f32x4 __attribute__((ext_vector_type(4)));

// DPP full-wave reductions (VALU-only). After row_shr:1/2/4/8 + row_bcast:15
// + row_bcast:31, lane 63 holds the 64-lane result. (Correctness-validated
// on HW in round 3.)
#define DPP_ADD(x, ctrl)                                                     \
  (x) += __int_as_float(__builtin_amdgcn_update_dpp(                         \
      0, __float_as_int(x), (ctrl), 0xF, 0xF, false))
#define DPP_MAX(x, ctrl)                                                     \
  do {                                                                       \
    float _t = __int_as_float(__builtin_amdgcn_update_dpp(                   \
        __float_as_int(x), __float_as_int(x), (ctrl), 0xF, 0xF, false));     \
    (x) = fmaxf((x), _t);                                                    \
  } while (0)

__device__ __forceinline__ float wave_sum63(float x) {
  DPP_ADD(x, 0x111); DPP_ADD(x, 0x112); DPP_ADD(x, 0x114); DPP_ADD(x, 0x118);
  DPP_ADD(x, 0x142); DPP_ADD(x, 0x143);
  return x;  // valid in lane 63
}
__device__ __forceinline__ float wave_max63(float x) {
  DPP_MAX(x, 0x111); DPP_MAX(x, 0x112); DPP_MAX(x, 0x114); DPP_MAX(x, 0x118);
  DPP_MAX(x, 0x142); DPP_MAX(x, 0x143);
  return x;  // valid in lane 63
}

__global__ __launch_bounds__(256, 2) void moe_fused_kernel(
    const float* __restrict__ hist, const float* __restrict__ W,
    const float* __restrict__ bias, const float* __restrict__ gu,
    float* __restrict__ out, int N)
{
    const int lane = threadIdx.x & 63;
    const int wid  = threadIdx.x >> 6;
    const int gw   = blockIdx.x * 4 + wid;      // global wave id
    const int GW   = gridDim.x * 4;             // total waves
    const int cbase = 4 * lane;

    // W fragments in registers: w{e}[j] = W[e][256*j + 4*lane .. +3]
    f32x4 w0[NITER], w1[NITER], w2[NITER], w3[NITER];
#pragma unroll
    for (int j = 0; j < NITER; ++j) {
        int c = 256 * j + cbase;
        w0[j] = *(const f32x4*)(W + 0 * HDIM + c);
        w1[j] = *(const f32x4*)(W + 1 * HDIM + c);
        w2[j] = *(const f32x4*)(W + 2 * HDIM + c);
        w3[j] = *(const f32x4*)(W + 3 * HDIM + c);
    }
    const float b0 = bias[0], b1 = bias[1], b2 = bias[2], b3 = bias[3];

    // ---- row loader (nontemporal: hist is a one-pass 1 GB stream) ----
    auto loadrow = [&](int row, f32x4* h, f32x4& u) {
        const float* hr = hist + (size_t)row * HDIM;
#pragma unroll
        for (int j = 0; j < NITER; ++j)
            h[j] = __builtin_nontemporal_load((const f32x4*)(hr + 256 * j + cbase));
        u = *(const f32x4*)(gu + (size_t)row * 4);
    };

    // ---- per-row compute + store (no DS ops anywhere) ----
    auto compute = [&](int row, const f32x4* h, f32x4 u4) {
        float d0 = 0.f, d1 = 0.f, d2 = 0.f, d3 = 0.f;
        float tot = 0.f, mx = -3.4e38f, cnt = 0.f;  // cnt = uq*4096 + pc (exact)

#pragma unroll
        for (int j = 0; j < NITER; ++j) {
            f32x4 v = h[j];
            d0 += v.x * w0[j].x + v.y * w0[j].y + v.z * w0[j].z + v.w * w0[j].w;
            d1 += v.x * w1[j].x + v.y * w1[j].y + v.z * w1[j].z + v.w * w1[j].w;
            d2 += v.x * w2[j].x + v.y * w2[j].y + v.z * w2[j].z + v.w * w2[j].w;
            d3 += v.x * w3[j].x + v.y * w3[j].y + v.z * w3[j].z + v.w * w3[j].w;
            tot += (v.x + v.y) + (v.z + v.w);
            mx = fmaxf(mx, fmaxf(fmaxf(v.x, v.y), fmaxf(v.z, v.w)));
            cnt += 4096.f * ((v.x != 0.f ? 1.f : 0.f) + (v.y != 0.f ? 1.f : 0.f)
                           + (v.z != 0.f ? 1.f : 0.f) + (v.w != 0.f ? 1.f : 0.f));
            // prev element (index 4*lane-1) via DPP wave_shr:1 (0x138):
            // lane i <- lane i-1's v.w; lane 0 (invalid) keeps `old`:
            //   j==0 : old = own v.x  -> diff 0 (first element has no prev)
            //   j>0  : old = splat of lane63's v.w from chunk j-1 (readlane)
            int old;
            if (j == 0) old = __float_as_int(v.x);
            else        old = __builtin_amdgcn_readlane(__float_as_int(h[j-1].w), 63);
            float prev = __int_as_float(__builtin_amdgcn_update_dpp(
                old, __float_as_int(v.w), 0x138, 0xF, 0xF, false));
            cnt += (v.x != prev ? 1.f : 0.f) + (v.y != v.x ? 1.f : 0.f)
                 + (v.z != v.y ? 1.f : 0.f) + (v.w != v.z ? 1.f : 0.f);
        }

        // VALU-only wave reductions; results valid in lane 63
        d0 = wave_sum63(d0); d1 = wave_sum63(d1);
        d2 = wave_sum63(d2); d3 = wave_sum63(d3);
        tot = wave_sum63(tot); cnt = wave_sum63(cnt); mx = wave_max63(mx);

        float uq = floorf(cnt * (1.f / 4096.f));
        float pc = cnt - 4096.f * uq;

        float z0 = d0 + b0, z1 = d1 + b1, z2 = d2 + b2, z3 = d3 + b3;
        {
            float ux = fminf(fmaxf(u4.x, 1e-6f), 1.f - 1e-6f);
            float uy = fminf(fmaxf(u4.y, 1e-6f), 1.f - 1e-6f);
            float uz = fminf(fmaxf(u4.z, 1e-6f), 1.f - 1e-6f);
            float uw = fminf(fmaxf(u4.w, 1e-6f), 1.f - 1e-6f);
            z0 += -logf(-logf(ux));
            z1 += -logf(-logf(uy));
            z2 += -logf(-logf(uz));
            z3 += -logf(-logf(uw));
        }
        float m  = fmaxf(fmaxf(z0, z1), fmaxf(z2, z3));
        float p0 = expf(z0 - m), p1 = expf(z1 - m);
        float p2 = expf(z2 - m), p3 = expf(z3 - m);
        float inv = 1.f / (p0 + p1 + p2 + p3);
        float freq = mx / (tot + 1e-6f);
        float res = (p0 * tot + p1 * freq + p2 * uq + p3 * pc) * inv;
        if (lane == 63) out[row] = res;
    };

    // ---- 2-row ping-pong pipeline: prefetch B while computing A ----
    f32x4 hA[NITER], hB[NITER];
    f32x4 uA, uB;
    if (gw < N) loadrow(gw, hA, uA);
    for (int row = gw; row < N; row += 2 * GW) {
        const int rB  = row + GW;
        const int rA2 = row + 2 * GW;
        if (rB < N) loadrow(rB, hB, uB);   // prefetch B (overlaps compute A)
        compute(row, hA, uA);
        if (rA2 < N) loadrow(rA2, hA, uA); // prefetch next A (overlaps compute B)
        if (rB < N) compute(rB, hB, uB);
    }
}

extern "C" void kernel_launch(void* const* d_in, const int* in_sizes, int n_in,
                              void* d_out, int out_size, void* d_ws, size_t ws_size,
                              hipStream_t stream) {
    const float* hist = (const float*)d_in[0];  // [N, 2048]
    const float* W    = (const float*)d_in[1];  // [4, 2048]
    const float* b    = (const float*)d_in[2];  // [4]
    const float* gu   = (const float*)d_in[3];  // [N, 4]
    float* out = (float*)d_out;                 // [N]
    const int N = out_size;

    dim3 grid(1024), block(256);
    moe_fused_kernel<<<grid, block, 0, stream>>>(hist, W, b, gu, out, N);
}